// Round 11
// baseline (209.513 us; speedup 1.0000x reference)
//
#include <hip/hip_runtime.h>
#include <hip/hip_bf16.h>

#define N_NODES 50000
#define N_EDGES 800000
#define DIN 256
#define DHID 128
#define DOUT 128
#define NBUCK 196     // buckets = dst >> 8
#define BINBLK 256    // binning blocks
#define EPB 3125      // edges per binning block (256*3125 = 800000 exact)
#define BINIT 13      // ceil(3125/256)

typedef __attribute__((ext_vector_type(8))) short bf16x8;
typedef __attribute__((ext_vector_type(16))) float f32x16;

__device__ inline unsigned short f2b(float f) {
    __hip_bfloat16 b = __float2bfloat16(f);
    return *reinterpret_cast<unsigned short*>(&b);
}

// ---------------- transpose+cast both weights in one dispatch
__global__ __launch_bounds__(256) void convW_kernel(
    const float* __restrict__ W1, const float* __restrict__ W2,
    unsigned short* __restrict__ W1t, unsigned short* __restrict__ W2t)
{
    int i = blockIdx.x * 256 + threadIdx.x;
    if (i < DIN * DHID) {
        int n = i >> 8, k = i & 255;
        W1t[i] = f2b(W1[k * DHID + n]);
    } else {
        int j = i - DIN * DHID;
        int n = j >> 7, k = j & 127;
        W2t[j] = f2b(W2[k * DOUT + n]);
    }
}

// ---------------- gemm1: hb = bf16( bf16(x) @ W1t^T ), MFMA 32x32x16, no LDS.
// One wave per 32 rows; B-fragments read from L2 (W1t 64KB, all-wave shared).
// Fused epilogue: es/ed via xor-shuffle reduce over the 32 col lanes.
__global__ __launch_bounds__(64) void gemm1_mfma(
    const float* __restrict__ x,
    const unsigned short* __restrict__ W1t,
    const float* __restrict__ att_src,
    const float* __restrict__ att_dst,
    unsigned short* __restrict__ hb,
    float* __restrict__ es,
    float* __restrict__ ed)
{
    const int lane = threadIdx.x;            // 0..63
    const int row0 = blockIdx.x * 32;
    const int c  = lane & 31;                // col within 32-tile / A row
    const int hf = lane >> 5;                // k-half

    int r  = row0 + c;
    int rc = (r < N_NODES) ? r : 0;          // clamp; stores guarded

    f32x16 acc[4];
    #pragma unroll
    for (int t = 0; t < 4; ++t)
        #pragma unroll
        for (int g = 0; g < 16; ++g) acc[t][g] = 0.f;

    const float* xr = x + (size_t)rc * DIN + hf * 8;
    const unsigned short* wb = W1t + hf * 8;

    #pragma unroll
    for (int kt = 0; kt < 16; ++kt) {
        float4 f0 = *(const float4*)(xr + kt * 16);
        float4 f1 = *(const float4*)(xr + kt * 16 + 4);
        bf16x8 a;
        a[0] = (short)f2b(f0.x); a[1] = (short)f2b(f0.y);
        a[2] = (short)f2b(f0.z); a[3] = (short)f2b(f0.w);
        a[4] = (short)f2b(f1.x); a[5] = (short)f2b(f1.y);
        a[6] = (short)f2b(f1.z); a[7] = (short)f2b(f1.w);
        #pragma unroll
        for (int t = 0; t < 4; ++t) {
            bf16x8 b = *(const bf16x8*)(wb + (size_t)(t * 32 + c) * DIN + kt * 16);
            acc[t] = __builtin_amdgcn_mfma_f32_32x32x16_bf16(a, b, acc[t], 0, 0, 0);
        }
    }

    // C/D: col = t*32 + c, row = row0 + (reg&3) + 4*hf + 8*(reg>>2)
    #pragma unroll
    for (int reg = 0; reg < 16; ++reg) {
        int row = row0 + (reg & 3) + 4 * hf + 8 * (reg >> 2);
        if (row < N_NODES) {
            #pragma unroll
            for (int t = 0; t < 4; ++t)
                hb[(size_t)row * DHID + t * 32 + c] = f2b(acc[t][reg]);
        }
    }

    // fused attention-logit dot products
    float esr[16], edr[16];
    #pragma unroll
    for (int reg = 0; reg < 16; ++reg) { esr[reg] = 0.f; edr[reg] = 0.f; }
    #pragma unroll
    for (int t = 0; t < 4; ++t) {
        float as = att_src[t * 32 + c];
        float ad = att_dst[t * 32 + c];
        #pragma unroll
        for (int reg = 0; reg < 16; ++reg) {
            esr[reg] += acc[t][reg] * as;
            edr[reg] += acc[t][reg] * ad;
        }
    }
    #pragma unroll
    for (int off = 16; off; off >>= 1)
        #pragma unroll
        for (int reg = 0; reg < 16; ++reg) {
            esr[reg] += __shfl_xor(esr[reg], off);
            edr[reg] += __shfl_xor(edr[reg], off);
        }
    if (c == 0) {
        #pragma unroll
        for (int reg = 0; reg < 16; ++reg) {
            int row = row0 + (reg & 3) + 4 * hf + 8 * (reg >> 2);
            if (row < N_NODES) { es[row] = esr[reg]; ed[row] = edr[reg]; }
        }
    }
}

// ---------------- per-block bucket histogram + global bucket totals
__global__ __launch_bounds__(256) void lhist_kernel(
    const int* __restrict__ ei, int* __restrict__ blockHist,
    int* __restrict__ bucketTotals)
{
    __shared__ int h[NBUCK];
    const int t = threadIdx.x, blk = blockIdx.x;
    if (t < NBUCK) h[t] = 0;
    __syncthreads();
    const int base = blk * EPB;
    #pragma unroll 1
    for (int it = 0; it < BINIT; ++it) {
        int e = base + it * 256 + t;
        if (e < base + EPB)
            atomicAdd(&h[ei[N_EDGES + e] >> 8], 1);
    }
    __syncthreads();
    if (t < NBUCK) {
        blockHist[t * 256 + blk] = h[t];
        atomicAdd(&bucketTotals[t], h[t]);
    }
}

// ---------------- fused scan: bucket-level exclusive scan (redundant per block)
// + row scan of blockHist -> matrixScan
__global__ __launch_bounds__(256) void scanfused_kernel(
    const int* __restrict__ bucketTotals,
    const int* __restrict__ blockHist,
    int* __restrict__ matrixScan)
{
    __shared__ int bs[256];
    __shared__ int s[256];
    const int t = threadIdx.x, b = blockIdx.x;

    bs[t] = (t < NBUCK) ? bucketTotals[t] : 0;
    __syncthreads();
    #pragma unroll
    for (int off = 1; off < 256; off <<= 1) {
        int u = (t >= off) ? bs[t - off] : 0;
        __syncthreads();
        bs[t] += u;
        __syncthreads();
    }
    const int base = (b == 0) ? 0 : bs[b - 1];

    int c = blockHist[b * 256 + t];
    s[t] = c;
    __syncthreads();
    #pragma unroll
    for (int off = 1; off < 256; off <<= 1) {
        int u = (t >= off) ? s[t - off] : 0;
        __syncthreads();
        s[t] += u;
        __syncthreads();
    }
    matrixScan[b * 256 + t] = base + s[t] - c;   // exclusive prefix
}

// ---------------- binpass: deterministic multi-split, per-(block,bucket) private ranges
__global__ __launch_bounds__(256) void binpass_kernel(
    const int* __restrict__ ei,
    const float* __restrict__ es,
    const float* __restrict__ ed,
    const int* __restrict__ matrixScan,
    int2* __restrict__ binned)
{
    __shared__ int lcur[NBUCK];
    const int t = threadIdx.x, blk = blockIdx.x;
    if (t < NBUCK) lcur[t] = matrixScan[t * 256 + blk];
    __syncthreads();
    const int base = blk * EPB;
    #pragma unroll 1
    for (int it = 0; it < BINIT; ++it) {
        int e = base + it * 256 + t;
        if (e < base + EPB) {
            int s = ei[e];
            int d = ei[N_EDGES + e];
            float a  = es[s] + ed[d];
            float sg = 1.f / (1.f + __expf(-a));
            float w  = __expf(sg);
            int pos = atomicAdd(&lcur[d >> 8], 1);
            binned[pos] = make_int2(s | ((d & 255) << 16), __float_as_int(w));
        }
    }
}

// ---------------- sortpass: one block per bucket; hist over dlow, scan, place.
__global__ __launch_bounds__(256) void sortpass_kernel(
    const int2* __restrict__ binned,
    const int* __restrict__ matrixScan,
    int2* __restrict__ sortedSW,
    int* __restrict__ offset,
    int* __restrict__ count)
{
    __shared__ int lhist[256], lscan[256], lcur[256];
    const int t = threadIdx.x, b = blockIdx.x;
    const int start = matrixScan[b * 256];
    const int end   = (b == NBUCK - 1) ? N_EDGES : matrixScan[(b + 1) * 256];
    const int cnt   = end - start;

    lhist[t] = 0;
    __syncthreads();
    for (int i = t; i < cnt; i += 256)
        atomicAdd(&lhist[(binned[start + i].x >> 16) & 255], 1);
    __syncthreads();

    int v = lhist[t];
    lscan[t] = v;
    __syncthreads();
    #pragma unroll
    for (int off = 1; off < 256; off <<= 1) {
        int u = (t >= off) ? lscan[t - off] : 0;
        __syncthreads();
        lscan[t] += u;
        __syncthreads();
    }
    int excl = lscan[t] - v;

    int node = (b << 8) + t;
    if (node < N_NODES) { offset[node] = start + excl; count[node] = v; }
    lcur[t] = excl;
    __syncthreads();

    for (int i = t; i < cnt; i += 256) {
        int2 ent = binned[start + i];
        int dlow = (ent.x >> 16) & 255;
        int pos = atomicAdd(&lcur[dlow], 1);
        sortedSW[start + pos] = make_int2(ent.x & 0xFFFF, ent.y);
    }
}

// ---------------- gather-aggregate: one wave/node; tiers 16/8/4/1 of MLP;
// fused epilogue: h1b = bf16(elu(acc/wsum)).
__global__ __launch_bounds__(256) void agg_kernel(
    const int2* __restrict__ sortedSW,
    const int* __restrict__ offset,
    const int* __restrict__ count,
    const unsigned short* __restrict__ hb,
    unsigned int* __restrict__ h1b)   // viewed as packed 2x bf16
{
    int node = (blockIdx.x * 256 + threadIdx.x) >> 6;
    int lane = threadIdx.x & 63;
    if (node >= N_NODES) return;

    int beg = offset[node];
    int deg = count[node];

    float2 acc = make_float2(0.f, 0.f);
    float wsum = 0.f;

    for (int base = 0; base < deg; base += 64) {
        int cnt = min(64, deg - base);
        int2 sw = (lane < cnt) ? sortedSW[beg + base + lane] : make_int2(0, 0);
        int j = 0;

#define TIER(T)                                                                 \
        for (; j + T <= cnt; j += T) {                                          \
            unsigned uu[T]; float ww[T];                                        \
            _Pragma("unroll")                                                   \
            for (int k = 0; k < T; ++k) {                                       \
                int s_ = __builtin_amdgcn_readlane(sw.x, j + k);                \
                uu[k] = *(const unsigned*)(hb + (size_t)s_ * DHID + 2 * lane);  \
            }                                                                   \
            _Pragma("unroll")                                                   \
            for (int k = 0; k < T; ++k)                                         \
                ww[k] = __uint_as_float(                                        \
                    (unsigned)__builtin_amdgcn_readlane(sw.y, j + k));          \
            _Pragma("unroll")                                                   \
            for (int k = 0; k < T; ++k) {                                       \
                wsum  += ww[k];                                                 \
                acc.x += ww[k] * __uint_as_float(uu[k] << 16);                  \
                acc.y += ww[k] * __uint_as_float(uu[k] & 0xffff0000u);          \
            }                                                                   \
        }

        TIER(16)
        TIER(8)
        TIER(4)
#undef TIER
        for (; j < cnt; ++j) {
            int   sj = __builtin_amdgcn_readlane(sw.x, j);
            float wj = __uint_as_float((unsigned)__builtin_amdgcn_readlane(sw.y, j));
            unsigned u = *(const unsigned*)(hb + (size_t)sj * DHID + 2 * lane);
            acc.x += wj * __uint_as_float(u << 16);
            acc.y += wj * __uint_as_float(u & 0xffff0000u);
            wsum  += wj;
        }
    }
    float inv = (deg > 0) ? 1.f / wsum : 0.f;
    float v0 = acc.x * inv, v1 = acc.y * inv;
    float e0 = v0 > 0.f ? v0 : (__expf(v0) - 1.f);
    float e1 = v1 > 0.f ? v1 : (__expf(v1) - 1.f);
    h1b[(size_t)node * (DHID / 2) + lane] =
        (unsigned)f2b(e0) | ((unsigned)f2b(e1) << 16);
}

// ---------------- gemm2: out(f32) = h1b @ W2t^T, MFMA 32x32x16, no LDS.
// W2t (32KB) read from L1/L2 directly.
__global__ __launch_bounds__(64) void gemm2_mfma(
    const unsigned short* __restrict__ h1b,
    const unsigned short* __restrict__ W2t,
    float* __restrict__ out)
{
    const int lane = threadIdx.x;
    const int row0 = blockIdx.x * 32;
    const int c  = lane & 31;
    const int hf = lane >> 5;

    int r  = row0 + c;
    int rc = (r < N_NODES) ? r : 0;

    f32x16 acc[4];
    #pragma unroll
    for (int t = 0; t < 4; ++t)
        #pragma unroll
        for (int g = 0; g < 16; ++g) acc[t][g] = 0.f;

    const unsigned short* ar = h1b + (size_t)rc * DHID + hf * 8;
    const unsigned short* wb = W2t + hf * 8;

    #pragma unroll
    for (int kt = 0; kt < 8; ++kt) {
        bf16x8 a = *(const bf16x8*)(ar + kt * 16);
        #pragma unroll
        for (int t = 0; t < 4; ++t) {
            bf16x8 b = *(const bf16x8*)(wb + (size_t)(t * 32 + c) * DHID + kt * 16);
            acc[t] = __builtin_amdgcn_mfma_f32_32x32x16_bf16(a, b, acc[t], 0, 0, 0);
        }
    }

    #pragma unroll
    for (int reg = 0; reg < 16; ++reg) {
        int row = row0 + (reg & 3) + 4 * hf + 8 * (reg >> 2);
        if (row < N_NODES) {
            #pragma unroll
            for (int t = 0; t < 4; ++t)
                out[(size_t)row * DOUT + t * 32 + c] = acc[t][reg];
        }
    }
}

extern "C" void kernel_launch(void* const* d_in, const int* in_sizes, int n_in,
                              void* d_out, int out_size, void* d_ws, size_t ws_size,
                              hipStream_t stream)
{
    const float* x    = (const float*)d_in[0];
    const int*   ei   = (const int*)d_in[1];
    const float* W1   = (const float*)d_in[2];
    const float* asrc = (const float*)d_in[3];
    const float* adst = (const float*)d_in[4];
    const float* W2   = (const float*)d_in[5];
    float*       out  = (float*)d_out;

    // ---- workspace layout (~40 MB) ----
    char* p = (char*)d_ws;
    unsigned short* hb  = (unsigned short*)p;  p += (size_t)N_NODES * DHID * 2;  // 12.8 MB
    unsigned int*   h1b = (unsigned int*)p;    p += (size_t)N_NODES * DHID * 2;  // 12.8 MB
    unsigned short* W1t = (unsigned short*)p;  p += (size_t)DHID * DIN * 2;      // 64 KB
    unsigned short* W2t = (unsigned short*)p;  p += (size_t)DOUT * DHID * 2;     // 32 KB
    float* es     = (float*)p;  p += (size_t)N_NODES * 4;
    float* ed     = (float*)p;  p += (size_t)N_NODES * 4;
    int*   offset = (int*)p;    p += (size_t)N_NODES * 4;
    int*   count  = (int*)p;    p += (size_t)N_NODES * 4;
    int*   blockHist    = (int*)p; p += (size_t)NBUCK * 256 * 4;                 // 200 KB
    int*   matrixScan   = (int*)p; p += (size_t)NBUCK * 256 * 4;                 // 200 KB
    int*   bucketTotals = (int*)p; p += 256 * 4;
    int2*  binned   = (int2*)p; p += (size_t)N_EDGES * 8;                        // 6.4 MB
    int2*  sortedSW = (int2*)p; p += (size_t)N_EDGES * 8;                        // 6.4 MB

    hipMemsetAsync(bucketTotals, 0, NBUCK * sizeof(int), stream);

    convW_kernel<<<(DIN * DHID + DHID * DOUT) / 256, 256, 0, stream>>>(W1, W2, W1t, W2t);

    gemm1_mfma<<<(N_NODES + 31) / 32, 64, 0, stream>>>(x, W1t, asrc, adst, hb, es, ed);

    lhist_kernel    <<<BINBLK, 256, 0, stream>>>(ei, blockHist, bucketTotals);
    scanfused_kernel<<<NBUCK, 256, 0, stream>>>(bucketTotals, blockHist, matrixScan);
    binpass_kernel  <<<BINBLK, 256, 0, stream>>>(ei, es, ed, matrixScan, binned);
    sortpass_kernel <<<NBUCK, 256, 0, stream>>>(binned, matrixScan, sortedSW, offset, count);

    agg_kernel<<<(N_NODES * 64 + 255) / 256, 256, 0, stream>>>(
        sortedSW, offset, count, hb, h1b);

    gemm2_mfma<<<(N_NODES + 31) / 32, 64, 0, stream>>>(
        (const unsigned short*)h1b, W2t, out);
}